// Round 10
// baseline (624.969 us; speedup 1.0000x reference)
//
#include <hip/hip_runtime.h>

#define B 8
#define N 1024
#define M 128
#define KF 16
#define C 16
#define DPE 64
#define NE 131072
#define NV (B*N)
#define NM (N*M)
#define BN_EPS 1e-5f

typedef short bf16x8 __attribute__((ext_vector_type(8)));
typedef float f32x4 __attribute__((ext_vector_type(4)));

__device__ inline unsigned short f2bf_rne(float f) {
    unsigned u = __float_as_uint(f);
    u += 0x7fffu + ((u >> 16) & 1u);
    return (unsigned short)(u >> 16);
}
__device__ inline void split_bf16(float v, unsigned short& hi, unsigned short& lo) {
    hi = f2bf_rne(v);
    float hf = __uint_as_float((unsigned)hi << 16);
    lo = f2bf_rne(v - hf);
}
union U4 { uint4 v; unsigned short s[8]; };

// Sf frag-major (uint4 units): SF4(b,nsub,ks,hl,l) ; el = S[n=16nsub+(l&15)][k=32ks+8(l>>4)+j]
__device__ __host__ inline size_t SF4(int b, int nsub, int ks, int hl, int l) {
    return ((((size_t)b * 64 + nsub) * 32 + ks) * 2 + hl) * 64 + l;
}
// Pf frag-major (uint4 units) per buffer: PF4(b,msub,ks,hl,l)
__device__ __host__ inline size_t PF4(int b, int msub, int ks, int hl, int l) {
    return ((((size_t)b * 8 + msub) * 32 + ks) * 2 + hl) * 64 + l;
}
#define PFBUF ((size_t)B * 8 * 32 * 2 * 64)   // uint4 per Pf buffer (4MB)

// ---------- prep: S -> frag-major hi/lo bf16 (XCD-aligned: b = blk&7) ----------
__global__ __launch_bounds__(256) void prep_s(const float* __restrict__ Lap, uint4* __restrict__ Sf) {
    int b = blockIdx.x & 7, nb = blockIdx.x >> 3;
    int t = threadIdx.x;
    int nl = t >> 4, kg = t & 15;
    int n = nb * 16 + nl;
    const float* row = Lap + ((size_t)b * N + n) * N;
    #pragma unroll
    for (int jj = 0; jj < 8; jj++) {
        int koct = kg + 16 * jj;
        int k0 = koct * 8;
        float4 f0 = *(const float4*)(row + k0);
        float4 f1 = *(const float4*)(row + k0 + 4);
        float e[8] = {f0.x, f0.y, f0.z, f0.w, f1.x, f1.y, f1.z, f1.w};
        U4 hi, lo;
        #pragma unroll
        for (int j = 0; j < 8; j++) split_bf16(e[j], hi.s[j], lo.s[j]);
        int ks = k0 >> 5;
        int lf = nl + 16 * (koct & 3);
        Sf[SF4(b, nb, ks, 0, lf)] = hi.v;
        Sf[SF4(b, nb, ks, 1, lf)] = lo.v;
    }
}

// ---------- prep: W -> feat plane0 (W^T, [m][node]) (XCD-aligned) ----------
__global__ __launch_bounds__(256) void prep_w_plane(const float* __restrict__ W, float* __restrict__ feat) {
    __shared__ float T[32][33];
    int b = blockIdx.x & 7;
    int tile = blockIdx.x >> 3;
    int nt = tile & 31, mt = tile >> 5;
    int n0 = nt * 32, m0 = mt * 32;
    int t = threadIdx.x;
    {
        int nl = t >> 3, mq = t & 7;
        float4 v = *(const float4*)(W + ((size_t)b * N + n0 + nl) * M + m0 + mq * 4);
        T[nl][mq * 4 + 0] = v.x; T[nl][mq * 4 + 1] = v.y;
        T[nl][mq * 4 + 2] = v.z; T[nl][mq * 4 + 3] = v.w;
    }
    __syncthreads();
    {
        int ml = t >> 3, nq = t & 7;
        float4 v = make_float4(T[nq * 4 + 0][ml], T[nq * 4 + 1][ml], T[nq * 4 + 2][ml], T[nq * 4 + 3][ml]);
        float* plane = feat + (size_t)b * KF * NM;
        *(float4*)(plane + (size_t)(m0 + ml) * N + n0 + nq * 4) = v;
    }
}

// ---------- prep: W -> Pf buffer 0 (XCD-aligned) ----------
__global__ __launch_bounds__(256) void prep_w_frag(const float* __restrict__ W, uint4* __restrict__ Pf) {
    int b = blockIdx.x & 7;
    int r = (blockIdx.x >> 3) * 256 + threadIdx.x;
    int msub = r >> 11, ks = (r >> 6) & 31, l = r & 63;
    int m = 16 * msub + (l & 15);
    U4 hi, lo;
    #pragma unroll
    for (int j = 0; j < 8; j++) {
        int n = 32 * ks + 8 * (l >> 4) + j;
        float v = W[((size_t)b * N + n) * M + m];
        split_bf16(v, hi.s[j], lo.s[j]);
    }
    Pf[PF4(b, msub, ks, 0, l)] = hi.v;
    Pf[PF4(b, msub, ks, 1, l)] = lo.v;
}

// ---------- MFMA gemm step: D = P^T @ S (bf16x3 split) ----------
// grid 512 (1D, b=blk&7 XCD-pinned): 2 blocks/CU -> two independent barrier
// domains per CU (one block's MFMA hides the other's barrier drain).
// Block: 256 thr = 4 waves; wave w owns msub 4*mh+w (16 m-rows) x 32 n, full K.
// BK=128: 8 chunks, 1 barrier each, double-buffered LDS (32KB).
__global__ __launch_bounds__(256) void gemm_step(const uint4* __restrict__ Sf,
                                                 const uint4* __restrict__ PfIn,
                                                 uint4* __restrict__ PfOut,
                                                 float* __restrict__ feat,
                                                 int kstep, int writePf) {
    __shared__ __align__(16) char smem[32768];
    uint4* ldsB = (uint4*)smem;               // 2 bufs x 1024 uint4 = 32 KB
    float* Dl = (float*)smem;                 // 64 x 36 floats (epilogue alias)

    int b = blockIdx.x & 7;
    int rest = blockIdx.x >> 3;               // 0..63
    int bx = rest & 31, mh = rest >> 5;
    int t = threadIdx.x;
    int w = t >> 6, lane = t & 63;
    int msub = 4 * mh + w;
    size_t sbase = SF4(b, 2 * bx, 0, 0, 0);

    f32x4 acc[2] = {};
    uint4 areg[2][4][2];                      // [ping][ksl][hl]
    uint4 breg[2][4];                         // [ping][q]

    // prologue: chunk 0
    #pragma unroll
    for (int q = 0; q < 4; q++) {
        int s = t + 256 * q;
        breg[0][q] = Sf[sbase + (size_t)(s >> 9) * 4096 + (s & 511)];
    }
    #pragma unroll
    for (int ksl = 0; ksl < 4; ksl++) {
        areg[0][ksl][0] = PfIn[PF4(b, msub, ksl, 0, lane)];
        areg[0][ksl][1] = PfIn[PF4(b, msub, ksl, 1, lane)];
    }

    #pragma unroll 2
    for (int ck = 0; ck < 8; ck++) {
        int p = ck & 1;
        if (ck < 7) {
            #pragma unroll
            for (int ksl = 0; ksl < 4; ksl++) {
                areg[p ^ 1][ksl][0] = PfIn[PF4(b, msub, 4 * (ck + 1) + ksl, 0, lane)];
                areg[p ^ 1][ksl][1] = PfIn[PF4(b, msub, 4 * (ck + 1) + ksl, 1, lane)];
            }
        }
        #pragma unroll
        for (int q = 0; q < 4; q++) ldsB[p * 1024 + t + 256 * q] = breg[p][q];
        if (ck < 7) {
            #pragma unroll
            for (int q = 0; q < 4; q++) {
                int s = t + 256 * q;
                breg[p ^ 1][q] = Sf[sbase + (size_t)(s >> 9) * 4096 + (size_t)(ck + 1) * 512 + (s & 511)];
            }
        }
        __syncthreads();
        #pragma unroll
        for (int ksl = 0; ksl < 4; ksl++) {
            bf16x8 bh[2], bl[2];
            #pragma unroll
            for (int ni = 0; ni < 2; ni++) {
                bh[ni] = __builtin_bit_cast(bf16x8, ldsB[p * 1024 + ni * 512 + ksl * 128 + lane]);
                bl[ni] = __builtin_bit_cast(bf16x8, ldsB[p * 1024 + ni * 512 + ksl * 128 + 64 + lane]);
            }
            bf16x8 ah = __builtin_bit_cast(bf16x8, areg[p][ksl][0]);
            bf16x8 al = __builtin_bit_cast(bf16x8, areg[p][ksl][1]);
            #pragma unroll
            for (int ni = 0; ni < 2; ni++) {
                acc[ni] = __builtin_amdgcn_mfma_f32_16x16x32_bf16(ah, bh[ni], acc[ni], 0, 0, 0);
                acc[ni] = __builtin_amdgcn_mfma_f32_16x16x32_bf16(ah, bl[ni], acc[ni], 0, 0, 0);
                acc[ni] = __builtin_amdgcn_mfma_f32_16x16x32_bf16(al, bh[ni], acc[ni], 0, 0, 0);
            }
        }
    }

    // ---- epilogue: Dl[m_blk(64)][36], then plane + frag writes ----
    __syncthreads();
    #pragma unroll
    for (int ni = 0; ni < 2; ni++)
        #pragma unroll
        for (int r = 0; r < 4; r++) {
            int m_blk = 16 * w + 4 * (lane >> 4) + r;
            int n = 16 * ni + (lane & 15);
            Dl[m_blk * 36 + n] = acc[ni][r];
        }
    __syncthreads();
    int n0 = 32 * bx;
    {   // f32 plane write ([m][node]); 256 threads x 8 floats
        int m_blk = t >> 2, c0 = (t & 3) * 8;
        int m = 64 * mh + m_blk;
        float* plane = feat + ((size_t)b * KF + (kstep + 1)) * NM + (size_t)m * N + n0 + c0;
        ((float4*)plane)[0] = *(const float4*)&Dl[m_blk * 36 + c0];
        ((float4*)plane)[1] = *(const float4*)&Dl[m_blk * 36 + c0 + 4];
    }
    if (writePf) {  // next-step A frags (hi/lo), ks = bx
        int msl = t >> 6, l = t & 63;
        int m_blk = 16 * msl + (l & 15);
        int ncol = 8 * (l >> 4);
        float4 v0 = *(const float4*)&Dl[m_blk * 36 + ncol];
        float4 v1 = *(const float4*)&Dl[m_blk * 36 + ncol + 4];
        float e[8] = {v0.x, v0.y, v0.z, v0.w, v1.x, v1.y, v1.z, v1.w};
        U4 hi, lo;
        #pragma unroll
        for (int j = 0; j < 8; j++) split_bf16(e[j], hi.s[j], lo.s[j]);
        PfOut[PF4(b, 4 * mh + msl, bx, 0, l)] = hi.v;
        PfOut[PF4(b, 4 * mh + msl, bx, 1, l)] = lo.v;
    }
}

// ---------- BN stats (XCD-aligned) ----------
__global__ __launch_bounds__(256) void bn_stats(const float* __restrict__ feat,
                                                const float* __restrict__ lin_w,
                                                const float* __restrict__ lin_b,
                                                float* __restrict__ stats) {
    __shared__ float wls[KF * C];
    __shared__ float red[4][2][C];
    int t = threadIdx.x;
    wls[t] = lin_w[t];
    __syncthreads();
    int b = blockIdx.x & 7;
    int i = (blockIdx.x >> 3) * 256 + t;
    const float4* fb = (const float4*)(feat + (size_t)b * KF * NM);

    float4 hacc[C];
    #pragma unroll
    for (int c = 0; c < C; c++) {
        float bb = lin_b[c];
        hacc[c] = make_float4(bb, bb, bb, bb);
    }
    for (int kk = 0; kk < KF; kk++) {
        float4 pv = fb[(size_t)kk * (NM / 4) + i];
        #pragma unroll
        for (int c = 0; c < C; c++) {
            float wv = wls[kk * C + c];
            hacc[c].x = fmaf(pv.x, wv, hacc[c].x);
            hacc[c].y = fmaf(pv.y, wv, hacc[c].y);
            hacc[c].z = fmaf(pv.z, wv, hacc[c].z);
            hacc[c].w = fmaf(pv.w, wv, hacc[c].w);
        }
    }
    float s[C], ss[C];
    #pragma unroll
    for (int c = 0; c < C; c++) {
        float4 h = hacc[c];
        s[c] = h.x + h.y + h.z + h.w;
        ss[c] = h.x * h.x + h.y * h.y + h.z * h.z + h.w * h.w;
    }
    #pragma unroll
    for (int off = 32; off > 0; off >>= 1)
        #pragma unroll
        for (int c = 0; c < C; c++) {
            s[c] += __shfl_down(s[c], off);
            ss[c] += __shfl_down(ss[c], off);
        }
    if ((t & 63) == 0) {
        int wv = t >> 6;
        #pragma unroll
        for (int c = 0; c < C; c++) { red[wv][0][c] = s[c]; red[wv][1][c] = ss[c]; }
    }
    __syncthreads();
    if (t < 32) {
        int which = t >> 4, c = t & 15;
        float v = red[0][which][c] + red[1][which][c] + red[2][which][c] + red[3][which][c];
        atomicAdd(&stats[b * 32 + which * 16 + c], v);
    }
}

// ---------- BN apply + relu + mean over M -> x ----------
__global__ __launch_bounds__(256) void bn_x(const float* __restrict__ feat,
                                            const float* __restrict__ lin_w,
                                            const float* __restrict__ lin_b,
                                            const float* __restrict__ gam,
                                            const float* __restrict__ bet,
                                            const float* __restrict__ stats,
                                            float* __restrict__ x) {
    __shared__ float wls[KF * C];
    __shared__ float red[8][32 * 17];
    int t = threadIdx.x;
    wls[t] = lin_w[t];
    __syncthreads();
    int grp = blockIdx.x;
    int b = grp & 7, n0 = (grp >> 3) * 32;
    int nl = t & 31, mg = t >> 5;
    int n = n0 + nl;

    const float inv_nm = 1.0f / (float)NM;
    float sc[C], sh[C], bb[C];
    #pragma unroll
    for (int c = 0; c < C; c++) {
        float mean = stats[b * 32 + c] * inv_nm;
        float var = stats[b * 32 + 16 + c] * inv_nm - mean * mean;
        sc[c] = gam[c] * rsqrtf(var + BN_EPS);
        sh[c] = bet[c] - mean * sc[c];
        bb[c] = lin_b[c];
    }
    const float* fb = feat + (size_t)b * KF * NM + n;
    float y[C] = {};
    for (int m = mg * 16; m < mg * 16 + 16; m++) {
        float p[KF];
        #pragma unroll
        for (int kk = 0; kk < KF; kk++) p[kk] = fb[(size_t)kk * NM + (size_t)m * N];
        #pragma unroll
        for (int c = 0; c < C; c++) {
            float h = bb[c];
            #pragma unroll
            for (int kk = 0; kk < KF; kk++) h = fmaf(p[kk], wls[kk * C + c], h);
            y[c] += fmaxf(fmaf(h, sc[c], sh[c]), 0.0f);
        }
    }
    #pragma unroll
    for (int c = 0; c < C; c++) red[mg][nl * 17 + c] = y[c];
    __syncthreads();
    #pragma unroll
    for (int q = 0; q < 2; q++) {
        int slot = t + q * 256;
        int snl = slot >> 4, c = slot & 15;
        float v = 0.0f;
        #pragma unroll
        for (int m8 = 0; m8 < 8; m8++) v += red[m8][snl * 17 + c];
        v *= (1.0f / (float)M);
        x[((size_t)b * N + n0 + snl) * C + c] = v;
    }
}

// ---------- edge CSR build ----------
__global__ __launch_bounds__(256) void edge_hist(const int* __restrict__ ei, int* __restrict__ cnt) {
    int e = blockIdx.x * 256 + threadIdx.x;
    bool is64 = (ei[1] == 0 && ei[3] == 0 && ei[5] == 0 && ei[7] == 0);
    int dst = is64 ? ei[2 * (NE + e)] : ei[NE + e];
    atomicAdd(&cnt[dst], 1);
}

__global__ __launch_bounds__(256) void edge_scan(const int* __restrict__ cnt,
                                                 int* __restrict__ off, int* __restrict__ cur) {
    __shared__ int ss[256];
    int t = threadIdx.x;
    int base = t * 32;
    int local[32];
    int s = 0;
    #pragma unroll
    for (int i = 0; i < 32; i++) { local[i] = cnt[base + i]; s += local[i]; }
    ss[t] = s;
    __syncthreads();
    #pragma unroll
    for (int d = 1; d < 256; d <<= 1) {
        int v = (t >= d) ? ss[t - d] : 0;
        __syncthreads();
        ss[t] += v;
        __syncthreads();
    }
    int excl = ss[t] - s;
    #pragma unroll
    for (int i = 0; i < 32; i++) { off[base + i] = excl; cur[base + i] = excl; excl += local[i]; }
}

__global__ __launch_bounds__(256) void edge_fill(const int* __restrict__ ei,
                                                 int* __restrict__ cur, int* __restrict__ bucket) {
    int e = blockIdx.x * 256 + threadIdx.x;
    bool is64 = (ei[1] == 0 && ei[3] == 0 && ei[5] == 0 && ei[7] == 0);
    int src, dst;
    if (is64) { src = ei[2 * e]; dst = ei[2 * (NE + e)]; }
    else      { src = ei[e];     dst = ei[NE + e]; }
    int pos = atomicAdd(&cur[dst], 1);
    bucket[pos] = src;
}

// ---------- fused gather + phi1 + phi2: out = relu(g@w1+b1)@w2+b2 ----------
// 16 nodes/block. g never materialized; h1 stays in LDS.
__global__ __launch_bounds__(256) void phi_fused(const int* __restrict__ cnt,
                                                 const int* __restrict__ off,
                                                 const int* __restrict__ bucket,
                                                 const float* __restrict__ x,
                                                 const float* __restrict__ w1,
                                                 const float* __restrict__ b1,
                                                 const float* __restrict__ w2,
                                                 const float* __restrict__ b2,
                                                 float* __restrict__ out) {
    __shared__ float w1s[C * DPE];     // 4 KB
    __shared__ float w2s[DPE * DPE];   // 16 KB
    __shared__ float b2s[DPE];
    __shared__ float gsh[16][17];
    __shared__ float h1sh[16][DPE];    // 4 KB
    int t = threadIdx.x;
    #pragma unroll
    for (int q = 0; q < 4; q++) w1s[t + q * 256] = w1[t + q * 256];
    #pragma unroll
    for (int q = 0; q < 16; q++) w2s[t + q * 256] = w2[t + q * 256];
    if (t < DPE) b2s[t] = b2[t];

    {   // gather: node nl, channel c
        int nl = t >> 4, c = t & 15;
        int n = blockIdx.x * 16 + nl;
        int o = off[n], d = cnt[n];
        float v = x[(size_t)n * C + c];
        int j = 0;
        for (; j + 4 <= d; j += 4) {
            int s0 = bucket[o + j], s1 = bucket[o + j + 1];
            int s2 = bucket[o + j + 2], s3 = bucket[o + j + 3];
            v += x[(size_t)s0 * C + c];
            v += x[(size_t)s1 * C + c];
            v += x[(size_t)s2 * C + c];
            v += x[(size_t)s3 * C + c];
        }
        for (; j < d; j++) v += x[(size_t)bucket[o + j] * C + c];
        gsh[nl][c] = v;
    }
    __syncthreads();
    #pragma unroll
    for (int q = 0; q < 4; q++) {       // phi1: 16 nodes x 64
        int item = t + 256 * q;
        int node = item >> 6, j = item & 63;
        float h = b1[j];
        #pragma unroll
        for (int c = 0; c < C; c++) h = fmaf(gsh[node][c], w1s[c * DPE + j], h);
        h1sh[node][j] = fmaxf(h, 0.0f);
    }
    __syncthreads();
    #pragma unroll
    for (int q = 0; q < 4; q++) {       // phi2: 16 nodes x 64
        int item = t + 256 * q;
        int node = item >> 6, d = item & 63;
        float o2 = b2s[d];
        #pragma unroll
        for (int j = 0; j < DPE; j++) o2 = fmaf(h1sh[node][j], w2s[j * DPE + d], o2);
        out[((size_t)blockIdx.x * 16 + node) * DPE + d] = o2;
    }
}

extern "C" void kernel_launch(void* const* d_in, const int* in_sizes, int n_in,
                              void* d_out, int out_size, void* d_ws, size_t ws_size,
                              hipStream_t stream) {
    const float* Lap   = (const float*)d_in[0];
    const float* W     = (const float*)d_in[1];
    const float* lin_w = (const float*)d_in[2];
    const float* lin_b = (const float*)d_in[3];
    const float* gam   = (const float*)d_in[4];
    const float* bet   = (const float*)d_in[5];
    const float* w1    = (const float*)d_in[6];
    const float* b1    = (const float*)d_in[7];
    const float* w2    = (const float*)d_in[8];
    const float* b2    = (const float*)d_in[9];
    const int*   ei    = (const int*)d_in[10];

    char* wsb = (char*)d_ws;
    float* feat  = (float*)wsb;                              // 64 MB
    uint4* Sf    = (uint4*)(wsb + ((size_t)64 << 20));       // 32 MB
    uint4* Pf    = (uint4*)(wsb + ((size_t)96 << 20));       // 8 MB (2 buffers)
    float* stats = (float*)(wsb + ((size_t)104 << 20));      // small tail region
    float* x     = stats + 1024;
    int*   cnt   = (int*)(x + (size_t)NV * C);
    int*   off   = cnt + NV;
    int*   cur   = off + NV;
    int*   bucket= cur + NV;                                 // NE ints
    float* out   = (float*)d_out;

    hipMemsetAsync(stats, 0, 2 * B * C * sizeof(float), stream);
    hipMemsetAsync(cnt, 0, NV * sizeof(int), stream);
    prep_s<<<dim3(512), 256, 0, stream>>>(Lap, Sf);
    prep_w_plane<<<dim3(1024), 256, 0, stream>>>(W, feat);
    prep_w_frag<<<dim3(512), 256, 0, stream>>>(W, Pf);
    for (int k = 0; k < KF - 1; k++)
        gemm_step<<<dim3(512), 256, 0, stream>>>(Sf, Pf + (k & 1) * PFBUF,
                                                 Pf + ((k + 1) & 1) * PFBUF, feat, k,
                                                 (k < KF - 2) ? 1 : 0);
    bn_stats<<<dim3(1024), 256, 0, stream>>>(feat, lin_w, lin_b, stats);
    bn_x<<<dim3(256), 256, 0, stream>>>(feat, lin_w, lin_b, gam, bet, stats, x);
    edge_hist<<<dim3(NE / 256), 256, 0, stream>>>(ei, cnt);
    edge_scan<<<dim3(1), 256, 0, stream>>>(cnt, off, cur);
    edge_fill<<<dim3(NE / 256), 256, 0, stream>>>(ei, cur, bucket);
    phi_fused<<<dim3(NV / 16), 256, 0, stream>>>(cnt, off, bucket, x, w1, b1, w2, b2, out);
}

// Round 11
// 547.056 us; speedup vs baseline: 1.1424x; 1.1424x over previous
//
#include <hip/hip_runtime.h>

#define B 8
#define N 1024
#define M 128
#define KF 16
#define C 16
#define DPE 64
#define NE 131072
#define NV (B*N)
#define NM (N*M)
#define BN_EPS 1e-5f

typedef short bf16x8 __attribute__((ext_vector_type(8)));
typedef float f32x4 __attribute__((ext_vector_type(4)));

__device__ inline unsigned short f2bf_rne(float f) {
    unsigned u = __float_as_uint(f);
    u += 0x7fffu + ((u >> 16) & 1u);
    return (unsigned short)(u >> 16);
}
__device__ inline void split_bf16(float v, unsigned short& hi, unsigned short& lo) {
    hi = f2bf_rne(v);
    float hf = __uint_as_float((unsigned)hi << 16);
    lo = f2bf_rne(v - hf);
}
union U4 { uint4 v; unsigned short s[8]; };

// Frag layout (uint4): base + rowsub*4096 + ks*128 + hl*64 + l
//   el = X[r=16*rowsub+(l&15)][k=32ks+8(l>>4)+j]
// Symmetric X serves as both MFMA A (X[m][k]) and B (B[k][n]=X[n][k]=X[k][n]).
#define SBS ((size_t)64 * 4096)        // batch stride for S/S2 frag arrays (4MB)
#define PBS ((size_t)16 * 8 * 4096)    // batch stride for Pfall (16 planes, 8MB)

struct Job {
    const uint4* Af; unsigned long long Abs;   // A frags (8 rowsubs)
    uint4* Of;       unsigned long long Obs;   // output frags (or null)
    float* Pl;                                  // f32 plane base (or null), bstride KF*NM
};
struct Jobs { Job j[9]; };

// ---------- prep: S -> frag-major hi/lo bf16 (XCD-aligned: b = blk&7) ----------
__global__ __launch_bounds__(256) void prep_s(const float* __restrict__ Lap, uint4* __restrict__ Sf) {
    int b = blockIdx.x & 7, nb = blockIdx.x >> 3;
    int t = threadIdx.x;
    int nl = t >> 4, kg = t & 15;
    int n = nb * 16 + nl;
    const float* row = Lap + ((size_t)b * N + n) * N;
    uint4* Sb = Sf + (size_t)b * SBS + (size_t)nb * 4096;
    #pragma unroll
    for (int jj = 0; jj < 8; jj++) {
        int koct = kg + 16 * jj;
        int k0 = koct * 8;
        float4 f0 = *(const float4*)(row + k0);
        float4 f1 = *(const float4*)(row + k0 + 4);
        float e[8] = {f0.x, f0.y, f0.z, f0.w, f1.x, f1.y, f1.z, f1.w};
        U4 hi, lo;
        #pragma unroll
        for (int j = 0; j < 8; j++) split_bf16(e[j], hi.s[j], lo.s[j]);
        int ks = k0 >> 5;
        int lf = nl + 16 * (koct & 3);
        Sb[ks * 128 + lf] = hi.v;
        Sb[ks * 128 + 64 + lf] = lo.v;
    }
}

// ---------- prep: W -> feat plane0 (W^T, [m][node]) (XCD-aligned) ----------
__global__ __launch_bounds__(256) void prep_w_plane(const float* __restrict__ W, float* __restrict__ feat) {
    __shared__ float T[32][33];
    int b = blockIdx.x & 7;
    int tile = blockIdx.x >> 3;
    int nt = tile & 31, mt = tile >> 5;
    int n0 = nt * 32, m0 = mt * 32;
    int t = threadIdx.x;
    {
        int nl = t >> 3, mq = t & 7;
        float4 v = *(const float4*)(W + ((size_t)b * N + n0 + nl) * M + m0 + mq * 4);
        T[nl][mq * 4 + 0] = v.x; T[nl][mq * 4 + 1] = v.y;
        T[nl][mq * 4 + 2] = v.z; T[nl][mq * 4 + 3] = v.w;
    }
    __syncthreads();
    {
        int ml = t >> 3, nq = t & 7;
        float4 v = make_float4(T[nq * 4 + 0][ml], T[nq * 4 + 1][ml], T[nq * 4 + 2][ml], T[nq * 4 + 3][ml]);
        float* plane = feat + (size_t)b * KF * NM;
        *(float4*)(plane + (size_t)(m0 + ml) * N + n0 + nq * 4) = v;
    }
}

// ---------- prep: W -> Pfall plane 0 (XCD-aligned) ----------
__global__ __launch_bounds__(256) void prep_w_frag(const float* __restrict__ W, uint4* __restrict__ Pfall) {
    int b = blockIdx.x & 7;
    int r = (blockIdx.x >> 3) * 256 + threadIdx.x;
    int msub = r >> 11, ks = (r >> 6) & 31, l = r & 63;
    int m = 16 * msub + (l & 15);
    U4 hi, lo;
    #pragma unroll
    for (int j = 0; j < 8; j++) {
        int n = 32 * ks + 8 * (l >> 4) + j;
        float v = W[((size_t)b * N + n) * M + m];
        split_bf16(v, hi.s[j], lo.s[j]);
    }
    uint4* dst = Pfall + (size_t)b * PBS + (size_t)msub * 4096 + ks * 128;
    dst[l] = hi.v;
    dst[64 + l] = lo.v;
}

// ---------- unified MFMA GEMM, job table (bf16x3 split) ----------
// blk = jid*256 + bx*8 + b : b=blk&7 XCD-pins batch b -> XCD b (L2 residency of
// B frags + A frags). Block = R9's proven shape: 512 thr = 8 waves, split-K
// (groups g=0/1 take K-halves), BK=64 chunks, double-buffered LDS, LDS acc
// reduction in epilogue. D = A(128 rows) x B(32 cols of N=1024).
__global__ __launch_bounds__(512) void gemm_job(const uint4* __restrict__ Bf, Jobs jobs) {
    __shared__ __align__(16) char smem[32768];
    uint4* ldsB = (uint4*)smem;               // [g][p][512] uint4 = 32 KB
    float* Dl = (float*)smem;                 // 128 x 36 floats (epilogue alias)
    f32x4* accbuf = (f32x4*)smem;             // epilogue alias

    Job jb = jobs.j[blockIdx.x >> 8];
    int b = blockIdx.x & 7;
    int bx = (blockIdx.x >> 3) & 31;
    int t = threadIdx.x;
    int w = t >> 6, lane = t & 63;
    int g = w >> 2, wp = w & 3;
    int u = t & 255;

    const uint4* Ab = jb.Af + (size_t)b * jb.Abs;
    const uint4* Bb = Bf + (size_t)b * SBS + (size_t)(2 * bx) * 4096;

    f32x4 acc[2][2] = {};
    uint4 areg[2][2][2][2];                   // [ping][ksl][mi][hl]
    uint4 breg[2][2];

    breg[0][0] = Bb[u + 256 * (8 * g)];
    breg[0][1] = Bb[4096 + u + 256 * (8 * g)];
    #pragma unroll
    for (int ksl = 0; ksl < 2; ksl++)
        #pragma unroll
        for (int mi = 0; mi < 2; mi++) {
            const uint4* a = Ab + (size_t)(2 * wp + mi) * 4096 + (16 * g + ksl) * 128;
            areg[0][ksl][mi][0] = a[lane];
            areg[0][ksl][mi][1] = a[64 + lane];
        }

    #pragma unroll 2
    for (int it = 0; it < 8; it++) {
        int p = it & 1;
        int ck = 8 * g + it;
        if (it < 7) {
            #pragma unroll
            for (int ksl = 0; ksl < 2; ksl++)
                #pragma unroll
                for (int mi = 0; mi < 2; mi++) {
                    const uint4* a = Ab + (size_t)(2 * wp + mi) * 4096 + (2 * (ck + 1) + ksl) * 128;
                    areg[p ^ 1][ksl][mi][0] = a[lane];
                    areg[p ^ 1][ksl][mi][1] = a[64 + lane];
                }
        }
        ldsB[g * 1024 + p * 512 + u] = breg[p][0];
        ldsB[g * 1024 + p * 512 + u + 256] = breg[p][1];
        if (it < 7) {
            breg[p ^ 1][0] = Bb[u + 256 * (size_t)(ck + 1)];
            breg[p ^ 1][1] = Bb[4096 + u + 256 * (size_t)(ck + 1)];
        }
        __syncthreads();
        #pragma unroll
        for (int ksl = 0; ksl < 2; ksl++) {
            bf16x8 bh[2], bl[2];
            #pragma unroll
            for (int ni = 0; ni < 2; ni++) {
                bh[ni] = __builtin_bit_cast(bf16x8, ldsB[g * 1024 + p * 512 + ni * 256 + ksl * 128 + lane]);
                bl[ni] = __builtin_bit_cast(bf16x8, ldsB[g * 1024 + p * 512 + ni * 256 + ksl * 128 + 64 + lane]);
            }
            #pragma unroll
            for (int mi = 0; mi < 2; mi++) {
                bf16x8 ah = __builtin_bit_cast(bf16x8, areg[p][ksl][mi][0]);
                bf16x8 al = __builtin_bit_cast(bf16x8, areg[p][ksl][mi][1]);
                #pragma unroll
                for (int ni = 0; ni < 2; ni++) {
                    acc[mi][ni] = __builtin_amdgcn_mfma_f32_16x16x32_bf16(ah, bh[ni], acc[mi][ni], 0, 0, 0);
                    acc[mi][ni] = __builtin_amdgcn_mfma_f32_16x16x32_bf16(ah, bl[ni], acc[mi][ni], 0, 0, 0);
                    acc[mi][ni] = __builtin_amdgcn_mfma_f32_16x16x32_bf16(al, bh[ni], acc[mi][ni], 0, 0, 0);
                }
            }
        }
    }

    // ---- epilogue: cross-group K-reduction, then plane + frag writes ----
    __syncthreads();
    if (g == 1) {
        #pragma unroll
        for (int mi = 0; mi < 2; mi++)
            #pragma unroll
            for (int ni = 0; ni < 2; ni++)
                accbuf[((wp * 2 + mi) * 2 + ni) * 64 + lane] = acc[mi][ni];
    }
    __syncthreads();
    if (g == 0) {
        #pragma unroll
        for (int mi = 0; mi < 2; mi++)
            #pragma unroll
            for (int ni = 0; ni < 2; ni++)
                acc[mi][ni] += accbuf[((wp * 2 + mi) * 2 + ni) * 64 + lane];
    }
    __syncthreads();
    if (g == 0) {
        #pragma unroll
        for (int mi = 0; mi < 2; mi++)
            #pragma unroll
            for (int ni = 0; ni < 2; ni++)
                #pragma unroll
                for (int r = 0; r < 4; r++) {
                    int m = 32 * wp + 16 * mi + 4 * (lane >> 4) + r;
                    int n = 16 * ni + (lane & 15);
                    Dl[m * 36 + n] = acc[mi][ni][r];
                }
    }
    __syncthreads();
    int n0 = 32 * bx;
    if (jb.Pl) {   // f32 plane write ([row][node]); 512 threads x 8 floats
        int m = t >> 2, c0 = (t & 3) * 8;
        float* plane = jb.Pl + (size_t)b * (KF * NM) + (size_t)m * N + n0 + c0;
        ((float4*)plane)[0] = *(const float4*)&Dl[m * 36 + c0];
        ((float4*)plane)[1] = *(const float4*)&Dl[m * 36 + c0 + 4];
    }
    if (jb.Of) {   // output frags (hi/lo), ks = bx
        int msub = t >> 6, l = t & 63;
        int m = 16 * msub + (l & 15);
        int ncol = 8 * (l >> 4);
        float4 v0 = *(const float4*)&Dl[m * 36 + ncol];
        float4 v1 = *(const float4*)&Dl[m * 36 + ncol + 4];
        float e[8] = {v0.x, v0.y, v0.z, v0.w, v1.x, v1.y, v1.z, v1.w};
        U4 hi, lo;
        #pragma unroll
        for (int j = 0; j < 8; j++) split_bf16(e[j], hi.s[j], lo.s[j]);
        uint4* Ob = jb.Of + (size_t)b * jb.Obs + (size_t)msub * 4096 + bx * 128;
        Ob[l] = hi.v;
        Ob[64 + l] = lo.v;
    }
}

// ---------- BN stats (XCD-aligned) ----------
__global__ __launch_bounds__(256) void bn_stats(const float* __restrict__ feat,
                                                const float* __restrict__ lin_w,
                                                const float* __restrict__ lin_b,
                                                float* __restrict__ stats) {
    __shared__ float wls[KF * C];
    __shared__ float red[4][2][C];
    int t = threadIdx.x;
    wls[t] = lin_w[t];
    __syncthreads();
    int b = blockIdx.x & 7;
    int i = (blockIdx.x >> 3) * 256 + t;
    const float4* fb = (const float4*)(feat + (size_t)b * KF * NM);

    float4 hacc[C];
    #pragma unroll
    for (int c = 0; c < C; c++) {
        float bb = lin_b[c];
        hacc[c] = make_float4(bb, bb, bb, bb);
    }
    for (int kk = 0; kk < KF; kk++) {
        float4 pv = fb[(size_t)kk * (NM / 4) + i];
        #pragma unroll
        for (int c = 0; c < C; c++) {
            float wv = wls[kk * C + c];
            hacc[c].x = fmaf(pv.x, wv, hacc[c].x);
            hacc[c].y = fmaf(pv.y, wv, hacc[c].y);
            hacc[c].z = fmaf(pv.z, wv, hacc[c].z);
            hacc[c].w = fmaf(pv.w, wv, hacc[c].w);
        }
    }
    float s[C], ss[C];
    #pragma unroll
    for (int c = 0; c < C; c++) {
        float4 h = hacc[c];
        s[c] = h.x + h.y + h.z + h.w;
        ss[c] = h.x * h.x + h.y * h.y + h.z * h.z + h.w * h.w;
    }
    #pragma unroll
    for (int off = 32; off > 0; off >>= 1)
        #pragma unroll
        for (int c = 0; c < C; c++) {
            s[c] += __shfl_down(s[c], off);
            ss[c] += __shfl_down(ss[c], off);
        }
    if ((t & 63) == 0) {
        int wv = t >> 6;
        #pragma unroll
        for (int c = 0; c < C; c++) { red[wv][0][c] = s[c]; red[wv][1][c] = ss[c]; }
    }
    __syncthreads();
    if (t < 32) {
        int which = t >> 4, c = t & 15;
        float v = red[0][which][c] + red[1][which][c] + red[2][which][c] + red[3][which][c];
        atomicAdd(&stats[b * 32 + which * 16 + c], v);
    }
}

// ---------- BN apply + relu + mean over M -> x ----------
__global__ __launch_bounds__(256) void bn_x(const float* __restrict__ feat,
                                            const float* __restrict__ lin_w,
                                            const float* __restrict__ lin_b,
                                            const float* __restrict__ gam,
                                            const float* __restrict__ bet,
                                            const float* __restrict__ stats,
                                            float* __restrict__ x) {
    __shared__ float wls[KF * C];
    __shared__ float red[8][32 * 17];
    int t = threadIdx.x;
    wls[t] = lin_w[t];
    __syncthreads();
    int grp = blockIdx.x;
    int b = grp & 7, n0 = (grp >> 3) * 32;
    int nl = t & 31, mg = t >> 5;
    int n = n0 + nl;

    const float inv_nm = 1.0f / (float)NM;
    float sc[C], sh[C], bb[C];
    #pragma unroll
    for (int c = 0; c < C; c++) {
        float mean = stats[b * 32 + c] * inv_nm;
        float var = stats[b * 32 + 16 + c] * inv_nm - mean * mean;
        sc[c] = gam[c] * rsqrtf(var + BN_EPS);
        sh[c] = bet[c] - mean * sc[c];
        bb[c] = lin_b[c];
    }
    const float* fb = feat + (size_t)b * KF * NM + n;
    float y[C] = {};
    for (int m = mg * 16; m < mg * 16 + 16; m++) {
        float p[KF];
        #pragma unroll
        for (int kk = 0; kk < KF; kk++) p[kk] = fb[(size_t)kk * NM + (size_t)m * N];
        #pragma unroll
        for (int c = 0; c < C; c++) {
            float h = bb[c];
            #pragma unroll
            for (int kk = 0; kk < KF; kk++) h = fmaf(p[kk], wls[kk * C + c], h);
            y[c] += fmaxf(fmaf(h, sc[c], sh[c]), 0.0f);
        }
    }
    #pragma unroll
    for (int c = 0; c < C; c++) red[mg][nl * 17 + c] = y[c];
    __syncthreads();
    #pragma unroll
    for (int q = 0; q < 2; q++) {
        int slot = t + q * 256;
        int snl = slot >> 4, c = slot & 15;
        float v = 0.0f;
        #pragma unroll
        for (int m8 = 0; m8 < 8; m8++) v += red[m8][snl * 17 + c];
        v *= (1.0f / (float)M);
        x[((size_t)b * N + n0 + snl) * C + c] = v;
    }
}

// ---------- edge CSR build + gather ----------
__global__ __launch_bounds__(256) void edge_hist(const int* __restrict__ ei, int* __restrict__ cnt) {
    int e = blockIdx.x * 256 + threadIdx.x;
    bool is64 = (ei[1] == 0 && ei[3] == 0 && ei[5] == 0 && ei[7] == 0);
    int dst = is64 ? ei[2 * (NE + e)] : ei[NE + e];
    atomicAdd(&cnt[dst], 1);
}

__global__ __launch_bounds__(256) void edge_scan(const int* __restrict__ cnt,
                                                 int* __restrict__ off, int* __restrict__ cur) {
    __shared__ int ss[256];
    int t = threadIdx.x;
    int base = t * 32;
    int local[32];
    int s = 0;
    #pragma unroll
    for (int i = 0; i < 32; i++) { local[i] = cnt[base + i]; s += local[i]; }
    ss[t] = s;
    __syncthreads();
    #pragma unroll
    for (int d = 1; d < 256; d <<= 1) {
        int v = (t >= d) ? ss[t - d] : 0;
        __syncthreads();
        ss[t] += v;
        __syncthreads();
    }
    int excl = ss[t] - s;
    #pragma unroll
    for (int i = 0; i < 32; i++) { off[base + i] = excl; cur[base + i] = excl; excl += local[i]; }
}

__global__ __launch_bounds__(256) void edge_fill(const int* __restrict__ ei,
                                                 int* __restrict__ cur, int* __restrict__ bucket) {
    int e = blockIdx.x * 256 + threadIdx.x;
    bool is64 = (ei[1] == 0 && ei[3] == 0 && ei[5] == 0 && ei[7] == 0);
    int src, dst;
    if (is64) { src = ei[2 * e]; dst = ei[2 * (NE + e)]; }
    else      { src = ei[e];     dst = ei[NE + e]; }
    int pos = atomicAdd(&cur[dst], 1);
    bucket[pos] = src;
}

__global__ __launch_bounds__(256) void edge_gather(const int* __restrict__ cnt,
                                                   const int* __restrict__ off,
                                                   const int* __restrict__ bucket,
                                                   const float* __restrict__ x,
                                                   float* __restrict__ g) {
    int t = threadIdx.x;
    int grp = t >> 4, c = t & 15;
    int n = blockIdx.x * 16 + grp;
    int o = off[n], d = cnt[n];
    float v = x[(size_t)n * C + c];
    int j = 0;
    for (; j + 4 <= d; j += 4) {
        int s0 = bucket[o + j], s1 = bucket[o + j + 1];
        int s2 = bucket[o + j + 2], s3 = bucket[o + j + 3];
        v += x[(size_t)s0 * C + c];
        v += x[(size_t)s1 * C + c];
        v += x[(size_t)s2 * C + c];
        v += x[(size_t)s3 * C + c];
    }
    for (; j < d; j++) v += x[(size_t)bucket[o + j] * C + c];
    g[(size_t)n * C + c] = v;
}

// ---------- phi ----------
__global__ __launch_bounds__(256) void phi1_k(const float* __restrict__ g,
                                              const float* __restrict__ w1,
                                              const float* __restrict__ b1,
                                              float* __restrict__ h1) {
    __shared__ float w1s[C * DPE];
    __shared__ float gs[4 * C];
    int t = threadIdx.x;
    int row0 = blockIdx.x * 4;
    #pragma unroll
    for (int q = 0; q < 4; q++) w1s[t + q * 256] = w1[t + q * 256];
    if (t < 64) gs[t] = g[row0 * C + t];
    __syncthreads();
    int r = t >> 6, j = t & 63;
    float h = b1[j];
    #pragma unroll
    for (int c = 0; c < C; c++) h = fmaf(gs[r * C + c], w1s[c * DPE + j], h);
    h1[(row0 + r) * DPE + j] = fmaxf(h, 0.0f);
}

__global__ __launch_bounds__(256) void phi2_k(const float* __restrict__ h1,
                                              const float* __restrict__ w2,
                                              const float* __restrict__ b2,
                                              float* __restrict__ out) {
    __shared__ float w2s[DPE * DPE];
    __shared__ float hs[4 * DPE];
    int t = threadIdx.x;
    int row0 = blockIdx.x * 4;
    #pragma unroll
    for (int q = 0; q < 16; q++) w2s[t + q * 256] = w2[t + q * 256];
    hs[t] = h1[row0 * DPE + t];
    __syncthreads();
    int r = t >> 6, d = t & 63;
    float o = b2[d];
    #pragma unroll
    for (int j = 0; j < DPE; j++) o = fmaf(hs[r * DPE + j], w2s[j * DPE + d], o);
    out[(row0 + r) * DPE + d] = o;
}

extern "C" void kernel_launch(void* const* d_in, const int* in_sizes, int n_in,
                              void* d_out, int out_size, void* d_ws, size_t ws_size,
                              hipStream_t stream) {
    const float* Lap   = (const float*)d_in[0];
    const float* W     = (const float*)d_in[1];
    const float* lin_w = (const float*)d_in[2];
    const float* lin_b = (const float*)d_in[3];
    const float* gam   = (const float*)d_in[4];
    const float* bet   = (const float*)d_in[5];
    const float* w1    = (const float*)d_in[6];
    const float* b1    = (const float*)d_in[7];
    const float* w2    = (const float*)d_in[8];
    const float* b2    = (const float*)d_in[9];
    const int*   ei    = (const int*)d_in[10];

    char* wsb = (char*)d_ws;
    float* feat  = (float*)wsb;                              // 64 MB
    uint4* Sf    = (uint4*)(wsb + ((size_t)64 << 20));       // 32 MB
    uint4* S2f   = (uint4*)(wsb + ((size_t)96 << 20));       // 32 MB
    uint4* Pfall = (uint4*)(wsb + ((size_t)128 << 20));      // 64 MB (16 plane frags)
    float* stats = (float*)(wsb + ((size_t)192 << 20));
    float* x     = stats + 1024;
    float* g     = x + (size_t)NV * C;
    float* h1    = g + (size_t)NV * C;
    int*   cnt   = (int*)(h1 + (size_t)NV * DPE);
    int*   off   = cnt + NV;
    int*   cur   = off + NV;
    int*   bucket= cur + NV;                                 // NE ints
    float* out   = (float*)d_out;

    auto PF  = [&](int p) { return Pfall + (size_t)p * 8 * 4096; };
    auto PLN = [&](int p) { return feat + (size_t)p * NM; };

    // d0: 8x S^2 tiles (A = S m-tile, out = S2f) + P1 = P0*S
    Jobs J0 = {};
    for (int jj = 0; jj < 8; jj++)
        J0.j[jj] = { Sf + (size_t)jj * 8 * 4096, SBS, S2f + (size_t)jj * 8 * 4096, SBS, nullptr };
    J0.j[8] = { PF(0), PBS, PF(1), PBS, PLN(1) };
    // duals s=0..6: {P_{2+2s} = P_{2s}*S^2, P_{3+2s} = P_{1+2s}*S^2}
    Jobs Jd[7];
    for (int s = 0; s < 7; s++) {
        Jd[s] = Jobs{};
        bool last = (s == 6);
        Jd[s].j[0] = { PF(2 * s),     PBS, last ? nullptr : PF(2 + 2 * s), PBS, PLN(2 + 2 * s) };
        Jd[s].j[1] = { PF(1 + 2 * s), PBS, last ? nullptr : PF(3 + 2 * s), PBS, PLN(3 + 2 * s) };
    }

    hipMemsetAsync(stats, 0, 2 * B * C * sizeof(float), stream);
    hipMemsetAsync(cnt, 0, NV * sizeof(int), stream);
    prep_s<<<dim3(512), 256, 0, stream>>>(Lap, Sf);
    prep_w_plane<<<dim3(1024), 256, 0, stream>>>(W, feat);
    prep_w_frag<<<dim3(512), 256, 0, stream>>>(W, Pfall);

    gemm_job<<<dim3(9 * 256), 512, 0, stream>>>(Sf, J0);
    for (int s = 0; s < 7; s++)
        gemm_job<<<dim3(2 * 256), 512, 0, stream>>>(S2f, Jd[s]);

    bn_stats<<<dim3(1024), 256, 0, stream>>>(feat, lin_w, lin_b, stats);
    bn_x<<<dim3(256), 256, 0, stream>>>(feat, lin_w, lin_b, gam, bet, stats, x);
    edge_hist<<<dim3(NE / 256), 256, 0, stream>>>(ei, cnt);
    edge_scan<<<dim3(1), 256, 0, stream>>>(cnt, off, cur);
    edge_fill<<<dim3(NE / 256), 256, 0, stream>>>(ei, cur, bucket);
    edge_gather<<<dim3(NV / 16), 256, 0, stream>>>(cnt, off, bucket, x, g);
    phi1_k<<<dim3(2048), 256, 0, stream>>>(g, w1, b1, h1);
    phi2_k<<<dim3(2048), 256, 0, stream>>>(h1, w2, b2, out);
}

// Round 12
// 473.982 us; speedup vs baseline: 1.3186x; 1.1542x over previous
//
#include <hip/hip_runtime.h>

#define B 8
#define N 1024
#define M 128
#define KF 16
#define C 16
#define DPE 64
#define NE 131072
#define NV (B*N)
#define NM (N*M)
#define BN_EPS 1e-5f

typedef short bf16x8 __attribute__((ext_vector_type(8)));
typedef float f32x4 __attribute__((ext_vector_type(4)));

__device__ inline unsigned short f2bf_rne(float f) {
    unsigned u = __float_as_uint(f);
    u += 0x7fffu + ((u >> 16) & 1u);
    return (unsigned short)(u >> 16);
}
__device__ inline void split_bf16(float v, unsigned short& hi, unsigned short& lo) {
    hi = f2bf_rne(v);
    float hf = __uint_as_float((unsigned)hi << 16);
    lo = f2bf_rne(v - hf);
}
union U4 { uint4 v; unsigned short s[8]; };

// Sf frag-major (uint4 units): SF4(b,nsub,ks,hl,l) ; el = S[n=16nsub+(l&15)][k=32ks+8(l>>4)+j]
__device__ __host__ inline size_t SF4(int b, int nsub, int ks, int hl, int l) {
    return ((((size_t)b * 64 + nsub) * 32 + ks) * 2 + hl) * 64 + l;
}
// Pf frag-major (uint4 units) per buffer: PF4(b,msub,ks,hl,l)
__device__ __host__ inline size_t PF4(int b, int msub, int ks, int hl, int l) {
    return ((((size_t)b * 8 + msub) * 32 + ks) * 2 + hl) * 64 + l;
}
#define PFBUF ((size_t)B * 8 * 32 * 2 * 64)   // uint4 per Pf buffer (4MB)

// ---------- prep: S -> frag-major hi/lo bf16 (XCD-aligned: b = blk&7) ----------
__global__ __launch_bounds__(256) void prep_s(const float* __restrict__ Lap, uint4* __restrict__ Sf) {
    int b = blockIdx.x & 7, nb = blockIdx.x >> 3;
    int t = threadIdx.x;
    int nl = t >> 4, kg = t & 15;
    int n = nb * 16 + nl;
    const float* row = Lap + ((size_t)b * N + n) * N;
    #pragma unroll
    for (int jj = 0; jj < 8; jj++) {
        int koct = kg + 16 * jj;
        int k0 = koct * 8;
        float4 f0 = *(const float4*)(row + k0);
        float4 f1 = *(const float4*)(row + k0 + 4);
        float e[8] = {f0.x, f0.y, f0.z, f0.w, f1.x, f1.y, f1.z, f1.w};
        U4 hi, lo;
        #pragma unroll
        for (int j = 0; j < 8; j++) split_bf16(e[j], hi.s[j], lo.s[j]);
        int ks = k0 >> 5;
        int lf = nl + 16 * (koct & 3);
        Sf[SF4(b, nb, ks, 0, lf)] = hi.v;
        Sf[SF4(b, nb, ks, 1, lf)] = lo.v;
    }
}

// ---------- prep: W -> feat plane0 (W^T, [m][node]) (XCD-aligned) ----------
__global__ __launch_bounds__(256) void prep_w_plane(const float* __restrict__ W, float* __restrict__ feat) {
    __shared__ float T[32][33];
    int b = blockIdx.x & 7;
    int tile = blockIdx.x >> 3;
    int nt = tile & 31, mt = tile >> 5;
    int n0 = nt * 32, m0 = mt * 32;
    int t = threadIdx.x;
    {
        int nl = t >> 3, mq = t & 7;
        float4 v = *(const float4*)(W + ((size_t)b * N + n0 + nl) * M + m0 + mq * 4);
        T[nl][mq * 4 + 0] = v.x; T[nl][mq * 4 + 1] = v.y;
        T[nl][mq * 4 + 2] = v.z; T[nl][mq * 4 + 3] = v.w;
    }
    __syncthreads();
    {
        int ml = t >> 3, nq = t & 7;
        float4 v = make_float4(T[nq * 4 + 0][ml], T[nq * 4 + 1][ml], T[nq * 4 + 2][ml], T[nq * 4 + 3][ml]);
        float* plane = feat + (size_t)b * KF * NM;
        *(float4*)(plane + (size_t)(m0 + ml) * N + n0 + nq * 4) = v;
    }
}

// ---------- prep: W -> Pf buffer 0 (XCD-aligned) ----------
__global__ __launch_bounds__(256) void prep_w_frag(const float* __restrict__ W, uint4* __restrict__ Pf) {
    int b = blockIdx.x & 7;
    int r = (blockIdx.x >> 3) * 256 + threadIdx.x;
    int msub = r >> 11, ks = (r >> 6) & 31, l = r & 63;
    int m = 16 * msub + (l & 15);
    U4 hi, lo;
    #pragma unroll
    for (int j = 0; j < 8; j++) {
        int n = 32 * ks + 8 * (l >> 4) + j;
        float v = W[((size_t)b * N + n) * M + m];
        split_bf16(v, hi.s[j], lo.s[j]);
    }
    Pf[PF4(b, msub, ks, 0, l)] = hi.v;
    Pf[PF4(b, msub, ks, 1, l)] = lo.v;
}

// ---------- MFMA gemm step: D = P^T @ S (bf16x3 split) ----------
// grid 256 1D (b=blk&7 XCD-pinned, R8-proven). Block: 1024 thr = 16 waves =
// 4 waves/SIMD (R9 had 2/SIMD): split-K into 4 groups x 4 chunks; identical
// total traffic to R9, double the latency-hiding TLP, half the mid-loop
// barriers. 4-way LDS acc reduction in epilogue (accbuf aliases staging LDS).
__global__ __launch_bounds__(1024) void gemm_step(const uint4* __restrict__ Sf,
                                                  const uint4* __restrict__ PfIn,
                                                  uint4* __restrict__ PfOut,
                                                  float* __restrict__ feat,
                                                  int kstep, int writePf) {
    __shared__ __align__(16) char smem[65536];
    uint4* ldsB = (uint4*)smem;               // [g(4)][p(2)][512] uint4 = 64 KB
    float* Dl = (float*)smem;                 // 128 x 36 floats (epilogue alias)
    f32x4* accbuf = (f32x4*)smem;             // [3][1024] f32x4 = 48 KB (epilogue alias)

    int b = blockIdx.x & 7, bx = blockIdx.x >> 3;   // XCD pinning
    int t = threadIdx.x;
    int w = t >> 6, lane = t & 63;
    int g = t >> 8, wp = w & 3;               // group 0..3, wave-in-group 0..3
    int u = t & 255;                          // group-local thread id

    size_t sbase = SF4(b, 2 * bx, 0, 0, 0);
    f32x4 acc[2][2] = {};
    uint4 areg[2][2][2][2];                   // [ping][ksl][mi][hl]
    uint4 breg[2][2];

    // prologue: group g's chunk 0 (ck = 4g); ks base = 8g
    breg[0][0] = Sf[sbase + u + 256 * (4 * g)];
    breg[0][1] = Sf[sbase + 4096 + u + 256 * (4 * g)];
    #pragma unroll
    for (int ksl = 0; ksl < 2; ksl++)
        #pragma unroll
        for (int mi = 0; mi < 2; mi++) {
            areg[0][ksl][mi][0] = PfIn[PF4(b, 2 * wp + mi, 8 * g + ksl, 0, lane)];
            areg[0][ksl][mi][1] = PfIn[PF4(b, 2 * wp + mi, 8 * g + ksl, 1, lane)];
        }

    #pragma unroll
    for (int it = 0; it < 4; it++) {
        int p = it & 1;
        int ck = 4 * g + it;
        if (it < 3) {
            #pragma unroll
            for (int ksl = 0; ksl < 2; ksl++)
                #pragma unroll
                for (int mi = 0; mi < 2; mi++) {
                    areg[p ^ 1][ksl][mi][0] = PfIn[PF4(b, 2 * wp + mi, 2 * (ck + 1) + ksl, 0, lane)];
                    areg[p ^ 1][ksl][mi][1] = PfIn[PF4(b, 2 * wp + mi, 2 * (ck + 1) + ksl, 1, lane)];
                }
        }
        ldsB[g * 1024 + p * 512 + u] = breg[p][0];
        ldsB[g * 1024 + p * 512 + u + 256] = breg[p][1];
        if (it < 3) {
            breg[p ^ 1][0] = Sf[sbase + u + 256 * (size_t)(ck + 1)];
            breg[p ^ 1][1] = Sf[sbase + 4096 + u + 256 * (size_t)(ck + 1)];
        }
        __syncthreads();
        #pragma unroll
        for (int ksl = 0; ksl < 2; ksl++) {
            bf16x8 bh[2], bl[2];
            #pragma unroll
            for (int ni = 0; ni < 2; ni++) {
                bh[ni] = __builtin_bit_cast(bf16x8, ldsB[g * 1024 + p * 512 + ni * 256 + ksl * 128 + lane]);
                bl[ni] = __builtin_bit_cast(bf16x8, ldsB[g * 1024 + p * 512 + ni * 256 + ksl * 128 + 64 + lane]);
            }
            #pragma unroll
            for (int mi = 0; mi < 2; mi++) {
                bf16x8 ah = __builtin_bit_cast(bf16x8, areg[p][ksl][mi][0]);
                bf16x8 al = __builtin_bit_cast(bf16x8, areg[p][ksl][mi][1]);
                #pragma unroll
                for (int ni = 0; ni < 2; ni++) {
                    acc[mi][ni] = __builtin_amdgcn_mfma_f32_16x16x32_bf16(ah, bh[ni], acc[mi][ni], 0, 0, 0);
                    acc[mi][ni] = __builtin_amdgcn_mfma_f32_16x16x32_bf16(ah, bl[ni], acc[mi][ni], 0, 0, 0);
                    acc[mi][ni] = __builtin_amdgcn_mfma_f32_16x16x32_bf16(al, bh[ni], acc[mi][ni], 0, 0, 0);
                }
            }
        }
    }

    // ---- epilogue: 4-way cross-group K-reduction, then plane + frag writes ----
    __syncthreads();
    if (g > 0) {
        #pragma unroll
        for (int mi = 0; mi < 2; mi++)
            #pragma unroll
            for (int ni = 0; ni < 2; ni++)
                accbuf[(size_t)(g - 1) * 1024 + ((wp * 2 + mi) * 2 + ni) * 64 + lane] = acc[mi][ni];
    }
    __syncthreads();
    if (g == 0) {
        #pragma unroll
        for (int q = 0; q < 3; q++)
            #pragma unroll
            for (int mi = 0; mi < 2; mi++)
                #pragma unroll
                for (int ni = 0; ni < 2; ni++)
                    acc[mi][ni] += accbuf[(size_t)q * 1024 + ((wp * 2 + mi) * 2 + ni) * 64 + lane];
    }
    __syncthreads();
    if (g == 0) {
        #pragma unroll
        for (int mi = 0; mi < 2; mi++)
            #pragma unroll
            for (int ni = 0; ni < 2; ni++)
                #pragma unroll
                for (int r = 0; r < 4; r++) {
                    int m = 32 * wp + 16 * mi + 4 * (lane >> 4) + r;
                    int n = 16 * ni + (lane & 15);
                    Dl[m * 36 + n] = acc[mi][ni][r];
                }
    }
    __syncthreads();
    int n0 = 32 * bx;
    {   // f32 plane write ([m][node]); 1024 threads x 4 floats
        int m = t >> 3, c0 = (t & 7) * 4;
        float* plane = feat + ((size_t)b * KF + (kstep + 1)) * NM + (size_t)m * N + n0 + c0;
        *(float4*)plane = *(const float4*)&Dl[m * 36 + c0];
    }
    if (writePf && t < 512) {  // next-step A frags (hi/lo), ks = bx
        int msub = t >> 6, l = t & 63;
        int m = 16 * msub + (l & 15);
        int ncol = 8 * (l >> 4);
        float4 v0 = *(const float4*)&Dl[m * 36 + ncol];
        float4 v1 = *(const float4*)&Dl[m * 36 + ncol + 4];
        float e[8] = {v0.x, v0.y, v0.z, v0.w, v1.x, v1.y, v1.z, v1.w};
        U4 hi, lo;
        #pragma unroll
        for (int j = 0; j < 8; j++) split_bf16(e[j], hi.s[j], lo.s[j]);
        PfOut[PF4(b, msub, bx, 0, l)] = hi.v;
        PfOut[PF4(b, msub, bx, 1, l)] = lo.v;
    }
}

// ---------- BN stats (XCD-aligned) ----------
__global__ __launch_bounds__(256) void bn_stats(const float* __restrict__ feat,
                                                const float* __restrict__ lin_w,
                                                const float* __restrict__ lin_b,
                                                float* __restrict__ stats) {
    __shared__ float wls[KF * C];
    __shared__ float red[4][2][C];
    int t = threadIdx.x;
    wls[t] = lin_w[t];
    __syncthreads();
    int b = blockIdx.x & 7;
    int i = (blockIdx.x >> 3) * 256 + t;
    const float4* fb = (const float4*)(feat + (size_t)b * KF * NM);

    float4 hacc[C];
    #pragma unroll
    for (int c = 0; c < C; c++) {
        float bb = lin_b[c];
        hacc[c] = make_float4(bb, bb, bb, bb);
    }
    for (int kk = 0; kk < KF; kk++) {
        float4 pv = fb[(size_t)kk * (NM / 4) + i];
        #pragma unroll
        for (int c = 0; c < C; c++) {
            float wv = wls[kk * C + c];
            hacc[c].x = fmaf(pv.x, wv, hacc[c].x);
            hacc[c].y = fmaf(pv.y, wv, hacc[c].y);
            hacc[c].z = fmaf(pv.z, wv, hacc[c].z);
            hacc[c].w = fmaf(pv.w, wv, hacc[c].w);
        }
    }
    float s[C], ss[C];
    #pragma unroll
    for (int c = 0; c < C; c++) {
        float4 h = hacc[c];
        s[c] = h.x + h.y + h.z + h.w;
        ss[c] = h.x * h.x + h.y * h.y + h.z * h.z + h.w * h.w;
    }
    #pragma unroll
    for (int off = 32; off > 0; off >>= 1)
        #pragma unroll
        for (int c = 0; c < C; c++) {
            s[c] += __shfl_down(s[c], off);
            ss[c] += __shfl_down(ss[c], off);
        }
    if ((t & 63) == 0) {
        int wv = t >> 6;
        #pragma unroll
        for (int c = 0; c < C; c++) { red[wv][0][c] = s[c]; red[wv][1][c] = ss[c]; }
    }
    __syncthreads();
    if (t < 32) {
        int which = t >> 4, c = t & 15;
        float v = red[0][which][c] + red[1][which][c] + red[2][which][c] + red[3][which][c];
        atomicAdd(&stats[b * 32 + which * 16 + c], v);
    }
}

// ---------- BN apply + relu + mean over M -> x ----------
__global__ __launch_bounds__(256) void bn_x(const float* __restrict__ feat,
                                            const float* __restrict__ lin_w,
                                            const float* __restrict__ lin_b,
                                            const float* __restrict__ gam,
                                            const float* __restrict__ bet,
                                            const float* __restrict__ stats,
                                            float* __restrict__ x) {
    __shared__ float wls[KF * C];
    __shared__ float red[8][32 * 17];
    int t = threadIdx.x;
    wls[t] = lin_w[t];
    __syncthreads();
    int grp = blockIdx.x;
    int b = grp & 7, n0 = (grp >> 3) * 32;
    int nl = t & 31, mg = t >> 5;
    int n = n0 + nl;

    const float inv_nm = 1.0f / (float)NM;
    float sc[C], sh[C], bb[C];
    #pragma unroll
    for (int c = 0; c < C; c++) {
        float mean = stats[b * 32 + c] * inv_nm;
        float var = stats[b * 32 + 16 + c] * inv_nm - mean * mean;
        sc[c] = gam[c] * rsqrtf(var + BN_EPS);
        sh[c] = bet[c] - mean * sc[c];
        bb[c] = lin_b[c];
    }
    const float* fb = feat + (size_t)b * KF * NM + n;
    float y[C] = {};
    for (int m = mg * 16; m < mg * 16 + 16; m++) {
        float p[KF];
        #pragma unroll
        for (int kk = 0; kk < KF; kk++) p[kk] = fb[(size_t)kk * NM + (size_t)m * N];
        #pragma unroll
        for (int c = 0; c < C; c++) {
            float h = bb[c];
            #pragma unroll
            for (int kk = 0; kk < KF; kk++) h = fmaf(p[kk], wls[kk * C + c], h);
            y[c] += fmaxf(fmaf(h, sc[c], sh[c]), 0.0f);
        }
    }
    #pragma unroll
    for (int c = 0; c < C; c++) red[mg][nl * 17 + c] = y[c];
    __syncthreads();
    #pragma unroll
    for (int q = 0; q < 2; q++) {
        int slot = t + q * 256;
        int snl = slot >> 4, c = slot & 15;
        float v = 0.0f;
        #pragma unroll
        for (int m8 = 0; m8 < 8; m8++) v += red[m8][snl * 17 + c];
        v *= (1.0f / (float)M);
        x[((size_t)b * N + n0 + snl) * C + c] = v;
    }
}

// ---------- edge CSR build + gather ----------
__global__ __launch_bounds__(256) void edge_hist(const int* __restrict__ ei, int* __restrict__ cnt) {
    int e = blockIdx.x * 256 + threadIdx.x;
    bool is64 = (ei[1] == 0 && ei[3] == 0 && ei[5] == 0 && ei[7] == 0);
    int dst = is64 ? ei[2 * (NE + e)] : ei[NE + e];
    atomicAdd(&cnt[dst], 1);
}

__global__ __launch_bounds__(256) void edge_scan(const int* __restrict__ cnt,
                                                 int* __restrict__ off, int* __restrict__ cur) {
    __shared__ int ss[256];
    int t = threadIdx.x;
    int base = t * 32;
    int local[32];
    int s = 0;
    #pragma unroll
    for (int i = 0; i < 32; i++) { local[i] = cnt[base + i]; s += local[i]; }
    ss[t] = s;
    __syncthreads();
    #pragma unroll
    for (int d = 1; d < 256; d <<= 1) {
        int v = (t >= d) ? ss[t - d] : 0;
        __syncthreads();
        ss[t] += v;
        __syncthreads();
    }
    int excl = ss[t] - s;
    #pragma unroll
    for (int i = 0; i < 32; i++) { off[base + i] = excl; cur[base + i] = excl; excl += local[i]; }
}

__global__ __launch_bounds__(256) void edge_fill(const int* __restrict__ ei,
                                                 int* __restrict__ cur, int* __restrict__ bucket) {
    int e = blockIdx.x * 256 + threadIdx.x;
    bool is64 = (ei[1] == 0 && ei[3] == 0 && ei[5] == 0 && ei[7] == 0);
    int src, dst;
    if (is64) { src = ei[2 * e]; dst = ei[2 * (NE + e)]; }
    else      { src = ei[e];     dst = ei[NE + e]; }
    int pos = atomicAdd(&cur[dst], 1);
    bucket[pos] = src;
}

__global__ __launch_bounds__(256) void edge_gather(const int* __restrict__ cnt,
                                                   const int* __restrict__ off,
                                                   const int* __restrict__ bucket,
                                                   const float* __restrict__ x,
                                                   float* __restrict__ g) {
    int t = threadIdx.x;
    int grp = t >> 4, c = t & 15;
    int n = blockIdx.x * 16 + grp;
    int o = off[n], d = cnt[n];
    float v = x[(size_t)n * C + c];
    int j = 0;
    for (; j + 4 <= d; j += 4) {
        int s0 = bucket[o + j], s1 = bucket[o + j + 1];
        int s2 = bucket[o + j + 2], s3 = bucket[o + j + 3];
        v += x[(size_t)s0 * C + c];
        v += x[(size_t)s1 * C + c];
        v += x[(size_t)s2 * C + c];
        v += x[(size_t)s3 * C + c];
    }
    for (; j < d; j++) v += x[(size_t)bucket[o + j] * C + c];
    g[(size_t)n * C + c] = v;
}

// ---------- phi ----------
__global__ __launch_bounds__(256) void phi1_k(const float* __restrict__ g,
                                              const float* __restrict__ w1,
                                              const float* __restrict__ b1,
                                              float* __restrict__ h1) {
    __shared__ float w1s[C * DPE];
    __shared__ float gs[4 * C];
    int t = threadIdx.x;
    int row0 = blockIdx.x * 4;
    #pragma unroll
    for (int q = 0; q < 4; q++) w1s[t + q * 256] = w1[t + q * 256];
    if (t < 64) gs[t] = g[row0 * C + t];
    __syncthreads();
    int r = t >> 6, j = t & 63;
    float h = b1[j];
    #pragma unroll
    for (int c = 0; c < C; c++) h = fmaf(gs[r * C + c], w1s[c * DPE + j], h);
    h1[(row0 + r) * DPE + j] = fmaxf(h, 0.0f);
}

__global__ __launch_bounds__(256) void phi2_k(const float* __restrict__ h1,
                                              const float* __restrict__ w2,
                                              const float* __restrict__ b2,
                                              float* __restrict__ out) {
    __shared__ float w2s[DPE * DPE];
    __shared__ float hs[4 * DPE];
    int t = threadIdx.x;
    int row0 = blockIdx.x * 4;
    #pragma unroll
    for (int q = 0; q < 16; q++) w2s[t + q * 256] = w2[t + q * 256];
    hs[t] = h1[row0 * DPE + t];
    __syncthreads();
    int r = t >> 6, d = t & 63;
    float o = b2[d];
    #pragma unroll
    for (int j = 0; j < DPE; j++) o = fmaf(hs[r * DPE + j], w2s[j * DPE + d], o);
    out[(row0 + r) * DPE + d] = o;
}

extern "C" void kernel_launch(void* const* d_in, const int* in_sizes, int n_in,
                              void* d_out, int out_size, void* d_ws, size_t ws_size,
                              hipStream_t stream) {
    const float* Lap   = (const float*)d_in[0];
    const float* W     = (const float*)d_in[1];
    const float* lin_w = (const float*)d_in[2];
    const float* lin_b = (const float*)d_in[3];
    const float* gam   = (const float*)d_in[4];
    const float* bet   = (const float*)d_in[5];
    const float* w1    = (const float*)d_in[6];
    const float* b1    = (const float*)d_in[7];
    const float* w2    = (const float*)d_in[8];
    const float* b2    = (const float*)d_in[9];
    const int*   ei    = (const int*)d_in[10];

    char* wsb = (char*)d_ws;
    float* feat  = (float*)wsb;                              // 64 MB
    uint4* Sf    = (uint4*)(wsb + ((size_t)64 << 20));       // 32 MB
    uint4* Pf    = (uint4*)(wsb + ((size_t)96 << 20));       // 8 MB (2 buffers)
    float* stats = (float*)(wsb + ((size_t)104 << 20));      // small tail region
    float* x     = stats + 1024;
    float* g     = x + (size_t)NV * C;
    float* h1    = g + (size_t)NV * C;
    int*   cnt   = (int*)(h1 + (size_t)NV * DPE);
    int*   off   = cnt + NV;
    int*   cur   = off + NV;
    int*   bucket= cur + NV;                                 // NE ints
    float* out   = (float*)d_out;

    hipMemsetAsync(stats, 0, 2 * B * C * sizeof(float), stream);
    hipMemsetAsync(cnt, 0, NV * sizeof(int), stream);
    prep_s<<<dim3(512), 256, 0, stream>>>(Lap, Sf);
    prep_w_plane<<<dim3(1024), 256, 0, stream>>>(W, feat);
    prep_w_frag<<<dim3(512), 256, 0, stream>>>(W, Pf);
    for (int k = 0; k < KF - 1; k++)
        gemm_step<<<dim3(256), 1024, 0, stream>>>(Sf, Pf + (k & 1) * PFBUF,
                                                  Pf + ((k + 1) & 1) * PFBUF, feat, k,
                                                  (k < KF - 2) ? 1 : 0);
    bn_stats<<<dim3(1024), 256, 0, stream>>>(feat, lin_w, lin_b, stats);
    bn_x<<<dim3(256), 256, 0, stream>>>(feat, lin_w, lin_b, gam, bet, stats, x);
    edge_hist<<<dim3(NE / 256), 256, 0, stream>>>(ei, cnt);
    edge_scan<<<dim3(1), 256, 0, stream>>>(cnt, off, cur);
    edge_fill<<<dim3(NE / 256), 256, 0, stream>>>(ei, cur, bucket);
    edge_gather<<<dim3(NV / 16), 256, 0, stream>>>(cnt, off, bucket, x, g);
    phi1_k<<<dim3(2048), 256, 0, stream>>>(g, w1, b1, h1);
    phi2_k<<<dim3(2048), 256, 0, stream>>>(h1, w2, b2, out);
}